// Round 1
// baseline (142.681 us; speedup 1.0000x reference)
//
#include <hip/hip_runtime.h>

// Problem constants
#define DD 48
#define HH 256
#define WW 256
#define DM 48
#define HM 128
#define WM 128
#define NPH 4

// Phase 0: straight copy of image (25 MB), vectorized float4
__global__ __launch_bounds__(256) void copy_phase0(const float4* __restrict__ src,
                                                   float4* __restrict__ dst, int n4) {
    int i = blockIdx.x * blockDim.x + threadIdx.x;
    if (i < n4) dst[i] = src[i];
}

// Phases 1..4: mvf upsample + scale + trilinear grid-sample
__global__ __launch_bounds__(256) void warp_kernel(
    const float* __restrict__ img,   // [48,256,256,2]
    const float* __restrict__ mvf,   // [4,3,48,128,128]
    float* __restrict__ out)         // [5,48,256,256,2]
{
    int gid = blockIdx.x * blockDim.x + threadIdx.x;
    // total = 4*48*256*256 = 12582912
    int x  = gid & 255;
    int y  = (gid >> 8) & 255;
    int zp = gid >> 16;           // 0 .. 191
    int z  = zp % 48;
    int ph = zp / 48;

    // ---- bilinear upsample of mvf (half-pixel, clamped == jax.image.resize 2x) ----
    float ys = fminf(fmaxf((float)y * 0.5f - 0.25f, 0.0f), (float)(HM - 1));
    float xs = fminf(fmaxf((float)x * 0.5f - 0.25f, 0.0f), (float)(WM - 1));
    int y0 = (int)ys;             // ys >= 0 -> trunc == floor
    int x0 = (int)xs;
    float wy = ys - (float)y0;
    float wx = xs - (float)x0;
    int y1 = min(y0 + 1, HM - 1);
    int x1 = min(x0 + 1, WM - 1);

    float w00 = (1.0f - wy) * (1.0f - wx);
    float w01 = (1.0f - wy) * wx;
    float w10 = wy * (1.0f - wx);
    float w11 = wy * wx;

    const float* mbase = mvf + (size_t)ph * 3 * (DM * HM * WM) + (size_t)z * (HM * WM);
    float mv[3];
#pragma unroll
    for (int c = 0; c < 3; ++c) {
        const float* m = mbase + (size_t)c * (DM * HM * WM);
        float v00 = m[y0 * WM + x0];
        float v01 = m[y0 * WM + x1];
        float v10 = m[y1 * WM + x0];
        float v11 = m[y1 * WM + x1];
        mv[c] = w00 * v00 + w01 * v01 + w10 * v10 + w11 * v11;
    }

    // ---- absolute sample coordinates (z,y,x) with channel scales (1,2,2) ----
    float zc = (float)z + mv[0];
    float yc = (float)y + 2.0f * mv[1];
    float xc = (float)x + 2.0f * mv[2];

    float z0f = floorf(zc), y0f = floorf(yc), x0f = floorf(xc);
    float wz2 = zc - z0f, wy2 = yc - y0f, wx2 = xc - x0f;
    int zi0 = (int)z0f, yi0 = (int)y0f, xi0 = (int)x0f;

    // ---- trilinear gather with zeros padding ----
    float acc0 = 0.0f, acc1 = 0.0f;
    const float2* img2 = (const float2*)img;
#pragma unroll
    for (int dz = 0; dz < 2; ++dz) {
        int  zi  = zi0 + dz;
        float wzv = dz ? wz2 : (1.0f - wz2);
        bool zok = (zi >= 0) && (zi < DD);
        int  zcl = min(max(zi, 0), DD - 1);
#pragma unroll
        for (int dy = 0; dy < 2; ++dy) {
            int  yi  = yi0 + dy;
            float wyv = dy ? wy2 : (1.0f - wy2);
            bool yok = (yi >= 0) && (yi < HH);
            int  ycl = min(max(yi, 0), HH - 1);
#pragma unroll
            for (int dx = 0; dx < 2; ++dx) {
                int  xi  = xi0 + dx;
                float wxv = dx ? wx2 : (1.0f - wx2);
                bool xok = (xi >= 0) && (xi < WW);
                int  xcl = min(max(xi, 0), WW - 1);
                float wgt = wzv * wyv * wxv;
                wgt = (zok && yok && xok) ? wgt : 0.0f;
                float2 v = img2[((size_t)zcl * HH + ycl) * WW + xcl];
                acc0 += wgt * v.x;
                acc1 += wgt * v.y;
            }
        }
    }

    float2* out2 = (float2*)out;
    size_t oidx = (((size_t)(ph + 1) * DD + z) * HH + y) * WW + x;
    out2[oidx] = make_float2(acc0, acc1);
}

extern "C" void kernel_launch(void* const* d_in, const int* in_sizes, int n_in,
                              void* d_out, int out_size, void* d_ws, size_t ws_size,
                              hipStream_t stream) {
    const float* img = (const float*)d_in[0];   // [1,1,48,256,256,2]
    const float* mvf = (const float*)d_in[1];   // [1,4,3,48,128,128]
    float* out = (float*)d_out;                 // [1,5,48,256,256,2]

    // Phase 0 copy: 48*256*256*2 = 6291456 floats = 1572864 float4
    int n4 = (DD * HH * WW * 2) / 4;
    copy_phase0<<<(n4 + 255) / 256, 256, 0, stream>>>((const float4*)img, (float4*)out, n4);

    // Warp phases: 4*48*256*256 threads
    int total = NPH * DD * HH * WW;
    warp_kernel<<<total / 256, 256, 0, stream>>>(img, mvf, out);
}

// Round 2
// 115.446 us; speedup vs baseline: 1.2359x; 1.2359x over previous
//
#include <hip/hip_runtime.h>

#define DD 48
#define HH 256
#define WW 256
#define DM 48
#define HM 128
#define WM 128
#define NPH 4
#define PLANE (DD * HH * WW)      // 3145728
#define MPLANE (DM * HM * WM)     // 786432

// One thread per (z,y,x). Computes phase-0 copy + all 4 warped phases.
__global__ __launch_bounds__(256) void mvf_warp_fused(
    const float* __restrict__ img,   // [48,256,256,2]
    const float* __restrict__ mvf,   // [4,3,48,128,128]
    float* __restrict__ out)         // [5,48,256,256,2]
{
    // XCD-chunked mapping: XCD k (= blockIdx % 8) owns y-band [32k, 32k+32),
    // sweeping y_local fast, z slow. Keeps each XCD's gather working set
    // (~few z-slices x 44 rows) resident in its private 4 MB L2.
    int b   = blockIdx.x;            // 0 .. 12287
    int xcd = b & 7;
    int c   = b >> 3;                // 0 .. 1535
    int z   = c >> 5;                // 0 .. 47
    int y   = (xcd << 5) | (c & 31); // 0 .. 255
    int x   = threadIdx.x;           // 0 .. 255

    const float2* img2 = (const float2*)img;
    float2* out2 = (float2*)out;

    int pidx = (z * HH + y) * WW + x;

    // ---- phase 0: copy ----
    out2[pidx] = img2[pidx];

    // ---- mvf bilinear position (half-pixel 2x upsample, clamped) ----
    float ys = fminf(fmaxf((float)y * 0.5f - 0.25f, 0.0f), (float)(HM - 1));
    float xs = fminf(fmaxf((float)x * 0.5f - 0.25f, 0.0f), (float)(WM - 1));
    // clamp corner to <= dim-2 so (c0, c0+1) is always in-bounds; weight adjusts
    int y0 = min((int)ys, HM - 2);
    int x0 = min((int)xs, WM - 2);
    float wy = ys - (float)y0;
    float wx = xs - (float)x0;
    float w00 = (1.0f - wy) * (1.0f - wx);
    float w01 = (1.0f - wy) * wx;
    float w10 = wy * (1.0f - wx);
    float w11 = wy * wx;

    int mbase = z * (HM * WM) + y0 * WM + x0;  // plane-local float offset

    float mvv[NPH][3];
#pragma unroll
    for (int ph = 0; ph < NPH; ++ph) {
#pragma unroll
        for (int ch = 0; ch < 3; ++ch) {
            const float* m = mvf + (ph * 3 + ch) * MPLANE + mbase;
            float2 a  = *(const float2*)m;
            float2 bb = *(const float2*)(m + WM);
            mvv[ph][ch] = w00 * a.x + w01 * a.y + w10 * bb.x + w11 * bb.y;
        }
    }

    // ---- 4 warped phases ----
#pragma unroll
    for (int ph = 0; ph < NPH; ++ph) {
        float zc = (float)z + mvv[ph][0];
        float yc = (float)y + 2.0f * mvv[ph][1];
        float xc = (float)x + 2.0f * mvv[ph][2];

        float zf = floorf(zc), yf = floorf(yc), xf = floorf(xc);
        int zi = (int)zf, yi = (int)yf, xi = (int)xf;
        float wz = zc - zf, wyg = yc - yf, wxg = xc - xf;

        float a0, a1;
        if (zi >= 0 && zi <= DD - 2 && yi >= 0 && yi <= HH - 2 &&
            xi >= 0 && xi <= WW - 2) {
            // fast path: fully in-bounds, no masks/clamps; each (z,y) corner
            // row = one float4 (x0,x1 pairs, both channels interleaved)
            const float* p = img + ((zi * HH + yi) * WW + xi) * 2;
            float4 v00 = *(const float4*)(p);
            float4 v01 = *(const float4*)(p + 2 * WW);
            float4 v10 = *(const float4*)(p + 2 * HH * WW);
            float4 v11 = *(const float4*)(p + 2 * HH * WW + 2 * WW);
            float u0 = 1.0f - wxg, u1 = wxg;
            float t0 = 1.0f - wyg, t1 = wyg;
            float s0 = 1.0f - wz,  s1 = wz;
            float c00 = u0 * v00.x + u1 * v00.z;
            float c01 = u0 * v01.x + u1 * v01.z;
            float c10 = u0 * v10.x + u1 * v10.z;
            float c11 = u0 * v11.x + u1 * v11.z;
            a0 = s0 * (t0 * c00 + t1 * c01) + s1 * (t0 * c10 + t1 * c11);
            float d00 = u0 * v00.y + u1 * v00.w;
            float d01 = u0 * v01.y + u1 * v01.w;
            float d10 = u0 * v10.y + u1 * v10.w;
            float d11 = u0 * v11.y + u1 * v11.w;
            a1 = s0 * (t0 * d00 + t1 * d01) + s1 * (t0 * d10 + t1 * d11);
        } else {
            // generic path: clamped indices, masked weights (zeros padding)
            a0 = 0.0f; a1 = 0.0f;
#pragma unroll
            for (int dz = 0; dz < 2; ++dz) {
                int  zz = zi + dz;
                float wzv = dz ? wz : (1.0f - wz);
                bool zok = (zz >= 0) && (zz < DD);
                int  zcl = min(max(zz, 0), DD - 1);
#pragma unroll
                for (int dy = 0; dy < 2; ++dy) {
                    int  yy = yi + dy;
                    float wyv = dy ? wyg : (1.0f - wyg);
                    bool yok = (yy >= 0) && (yy < HH);
                    int  ycl = min(max(yy, 0), HH - 1);
#pragma unroll
                    for (int dx = 0; dx < 2; ++dx) {
                        int  xx = xi + dx;
                        float wxv = dx ? wxg : (1.0f - wxg);
                        bool xok = (xx >= 0) && (xx < WW);
                        int  xcl = min(max(xx, 0), WW - 1);
                        float wgt = (zok && yok && xok) ? wzv * wyv * wxv : 0.0f;
                        float2 v = img2[(zcl * HH + ycl) * WW + xcl];
                        a0 += wgt * v.x;
                        a1 += wgt * v.y;
                    }
                }
            }
        }
        out2[(ph + 1) * PLANE + pidx] = make_float2(a0, a1);
    }
}

extern "C" void kernel_launch(void* const* d_in, const int* in_sizes, int n_in,
                              void* d_out, int out_size, void* d_ws, size_t ws_size,
                              hipStream_t stream) {
    const float* img = (const float*)d_in[0];   // [1,1,48,256,256,2]
    const float* mvf = (const float*)d_in[1];   // [1,4,3,48,128,128]
    float* out = (float*)d_out;                 // [1,5,48,256,256,2]

    int nblk = (DD * HH) >> 0;                  // 12288 blocks of 256 threads
    mvf_warp_fused<<<dim3(nblk * 1), 256, 0, stream>>>(img, mvf, out);
}

// Round 3
// 104.088 us; speedup vs baseline: 1.3708x; 1.1091x over previous
//
#include <hip/hip_runtime.h>

#define DD 48
#define HH 256
#define WW 256
#define HM 128
#define WM 128
#define NPH 4
#define PLANE (DD * HH * WW)      // 3145728
#define MPLANE (DD * HM * WM)     // 786432

// One thread per (z,y,x). Phase-0 copy + 4 warped phases, fully branchless,
// all gather loads batched for max memory-level parallelism.
__global__ __launch_bounds__(256, 4) void mvf_warp_fused(
    const float* __restrict__ img,   // [48,256,256,2]
    const float* __restrict__ mvf,   // [4,3,48,128,128]
    float* __restrict__ out)         // [5,48,256,256,2]
{
    // XCD-chunked: XCD k (= blockIdx%8) owns y-band [32k,32k+32), z swept slow.
    int b   = blockIdx.x;            // 0 .. 12287
    int xcd = b & 7;
    int c   = b >> 3;
    int z   = c >> 5;                // 0 .. 47
    int y   = (xcd << 5) | (c & 31); // 0 .. 255
    int x   = threadIdx.x;           // 0 .. 255

    const float2* img2 = (const float2*)img;
    float2* out2 = (float2*)out;
    int pidx = (z * HH + y) * WW + x;

    // ---- phase 0: copy ----
    out2[pidx] = img2[pidx];

    // ---- mvf bilinear weights (2x half-pixel upsample, clamped) ----
    float ys = fminf(fmaxf((float)y * 0.5f - 0.25f, 0.0f), (float)(HM - 1));
    float xs = fminf(fmaxf((float)x * 0.5f - 0.25f, 0.0f), (float)(WM - 1));
    int y0 = min((int)ys, HM - 2);
    int x0 = min((int)xs, WM - 2);
    float wy = ys - (float)y0;
    float wx = xs - (float)x0;
    float w00 = (1.0f - wy) * (1.0f - wx);
    float w01 = (1.0f - wy) * wx;
    float w10 = wy * (1.0f - wx);
    float w11 = wy * wx;
    int mbase = z * (HM * WM) + y0 * WM + x0;

    // ---- batch all 24 mvf loads ----
    float2 ma[12], mb[12];
#pragma unroll
    for (int i = 0; i < 12; ++i) {
        const float* m = mvf + i * MPLANE + mbase;
        ma[i] = *(const float2*)m;
        mb[i] = *(const float2*)(m + WM);
    }
    float mvv[NPH][3];
#pragma unroll
    for (int ph = 0; ph < NPH; ++ph)
#pragma unroll
        for (int ch = 0; ch < 3; ++ch) {
            int i = ph * 3 + ch;
            mvv[ph][ch] = w00 * ma[i].x + w01 * ma[i].y + w10 * mb[i].x + w11 * mb[i].y;
        }

    // ---- compute all addresses + masked weights (branchless) ----
    int   off[NPH][4];
    float s0[NPH], s1[NPH], t0[NPH], t1[NPH], sw0[NPH], sw1[NPH];
#pragma unroll
    for (int ph = 0; ph < NPH; ++ph) {
        float zc = (float)z + mvv[ph][0];
        float yc = (float)y + 2.0f * mvv[ph][1];
        float xc = (float)x + 2.0f * mvv[ph][2];
        float zf = floorf(zc), yf = floorf(yc), xf = floorf(xc);
        int zi = (int)zf, yi = (int)yf, xi = (int)xf;
        float wz = zc - zf, wyg = yc - yf, wxg = xc - xf;

        int zc0 = min(max(zi,     0), DD - 1);
        int zc1 = min(max(zi + 1, 0), DD - 1);
        int yc0 = min(max(yi,     0), HH - 1);
        int yc1 = min(max(yi + 1, 0), HH - 1);
        int xb  = min(max(xi,     0), WW - 2);

        s0[ph] = (zi     >= 0 && zi     < DD) ? (1.0f - wz)  : 0.0f;
        s1[ph] = (zi + 1 >= 0 && zi + 1 < DD) ? wz           : 0.0f;
        t0[ph] = (yi     >= 0 && yi     < HH) ? (1.0f - wyg) : 0.0f;
        t1[ph] = (yi + 1 >= 0 && yi + 1 < HH) ? wyg          : 0.0f;
        // x handled via slot-shift: loaded pair is (xb, xb+1); corner xi sits
        // at slot d, corner xi+1 at slot d+1, d = xi - xb in {-1,0,1} (else OOB)
        int d = xi - xb;
        sw0[ph] = (d == 0) ? (1.0f - wxg) : ((d == -1) ? wxg : 0.0f);
        sw1[ph] = (d == 0) ? wxg : ((d == 1) ? (1.0f - wxg) : 0.0f);

        off[ph][0] = (zc0 * HH + yc0) * WW + xb;
        off[ph][1] = (zc0 * HH + yc1) * WW + xb;
        off[ph][2] = (zc1 * HH + yc0) * WW + xb;
        off[ph][3] = (zc1 * HH + yc1) * WW + xb;
    }

    // ---- issue ALL 16 gathers back-to-back (16 float4 in flight) ----
    float4 v[NPH][4];
#pragma unroll
    for (int ph = 0; ph < NPH; ++ph)
#pragma unroll
        for (int k = 0; k < 4; ++k) {
            const float2* p = img2 + off[ph][k];
            float2 lo = p[0], hi = p[1];
            v[ph][k] = make_float4(lo.x, lo.y, hi.x, hi.y);
        }

    // ---- combine + store ----
#pragma unroll
    for (int ph = 0; ph < NPH; ++ph) {
        float r0a = sw0[ph] * v[ph][0].x + sw1[ph] * v[ph][0].z;
        float r0b = sw0[ph] * v[ph][0].y + sw1[ph] * v[ph][0].w;
        float r1a = sw0[ph] * v[ph][1].x + sw1[ph] * v[ph][1].z;
        float r1b = sw0[ph] * v[ph][1].y + sw1[ph] * v[ph][1].w;
        float r2a = sw0[ph] * v[ph][2].x + sw1[ph] * v[ph][2].z;
        float r2b = sw0[ph] * v[ph][2].y + sw1[ph] * v[ph][2].w;
        float r3a = sw0[ph] * v[ph][3].x + sw1[ph] * v[ph][3].z;
        float r3b = sw0[ph] * v[ph][3].y + sw1[ph] * v[ph][3].w;
        float a0 = s0[ph] * (t0[ph] * r0a + t1[ph] * r1a)
                 + s1[ph] * (t0[ph] * r2a + t1[ph] * r3a);
        float a1 = s0[ph] * (t0[ph] * r0b + t1[ph] * r1b)
                 + s1[ph] * (t0[ph] * r2b + t1[ph] * r3b);
        out2[(ph + 1) * PLANE + pidx] = make_float2(a0, a1);
    }
}

extern "C" void kernel_launch(void* const* d_in, const int* in_sizes, int n_in,
                              void* d_out, int out_size, void* d_ws, size_t ws_size,
                              hipStream_t stream) {
    const float* img = (const float*)d_in[0];   // [1,1,48,256,256,2]
    const float* mvf = (const float*)d_in[1];   // [1,4,3,48,128,128]
    float* out = (float*)d_out;                 // [1,5,48,256,256,2]

    mvf_warp_fused<<<DD * HH, 256, 0, stream>>>(img, mvf, out);
}